// Round 9
// baseline (205.806 us; speedup 1.0000x reference)
//
#include <hip/hip_runtime.h>
#include <math.h>

// Problem constants
#define B_    4
#define LQ_   1024
#define LKV_  4096
#define DM    512    // model dim
#define NH    4
#define HD_   128    // head dim

typedef _Float16 half8   __attribute__((ext_vector_type(8)));
typedef _Float16 half4_t __attribute__((ext_vector_type(4)));
typedef float    floatx4 __attribute__((ext_vector_type(4)));

#define MFMA16(a, b, c) __builtin_amdgcn_mfma_f32_16x16x32_f16((a), (b), (c), 0, 0, 0)

// XOR swizzle: power-of-2 row strides + per-row column xor keeps 16B alignment
// and spreads 16-row fragment reads across all 32 banks (<=2-way, free).
#define SWZ(c, r) ((c) ^ (((r) & 7) << 3))

// ---------------------------------------------------------------------------
// prep: cast the 4 weight matrices to f16.
// ---------------------------------------------------------------------------
__global__ __launch_bounds__(256) void prep_w(
    const float* __restrict__ Wq, const float* __restrict__ Wk,
    const float* __restrict__ Wv, const float* __restrict__ Wo,
    _Float16* __restrict__ Wh)
{
  int i = blockIdx.x * 256 + threadIdx.x;   // 0..262143
  int wsel = i >> 16;                       // 65536 float4 per W
  const float* src = (wsel == 0) ? Wq : (wsel == 1) ? Wk : (wsel == 2) ? Wv : Wo;
  size_t off = i & 65535;
  float4 v = *(const float4*)(src + off * 4);
  half4_t h;
  h[0] = (_Float16)v.x; h[1] = (_Float16)v.y;
  h[2] = (_Float16)v.z; h[3] = (_Float16)v.w;
  *(half4_t*)(Wh + ((size_t)wsel << 18) + off * 4) = h;
}

// ---------------------------------------------------------------------------
// Fused Q+K+V projection. Grid (160, 4):
//   bx <  128 : KV path — dual GEMM vs enc rows [bx*128, +128):
//               K row-major f16, V transposed per-head to Vt.
//   bx >= 128 : Q path  — GEMM vs x rows [(bx-128)*128, +128), f16 out *qscale.
// ---------------------------------------------------------------------------
__global__ __launch_bounds__(256, 2) void proj_qkv(
    const float* __restrict__ x,       // [4096, 512] f32
    const float* __restrict__ enc,     // [16384, 512] f32
    const _Float16* __restrict__ Whq,
    const _Float16* __restrict__ Whk,
    const _Float16* __restrict__ Whv,
    const float* __restrict__ bq,
    const float* __restrict__ bk,
    const float* __restrict__ bv,
    _Float16* __restrict__ Qh,
    _Float16* __restrict__ Kh,
    _Float16* __restrict__ Vt,
    float qscale)
{
  __shared__ _Float16 SM[3 * 128 * 72];          // 55,296 B
  _Float16 (*Xs)[72]  = (_Float16(*)[72])SM;
  _Float16 (*Ws1)[72] = (_Float16(*)[72])(SM + 128 * 72);
  _Float16 (*Ws2)[72] = (_Float16(*)[72])(SM + 2 * 128 * 72);

  const int tid  = threadIdx.x;
  const int lane = tid & 63;
  const int w    = tid >> 6;
  const int n16  = lane & 15;
  const int quad = lane >> 4;
  const int wm   = (w & 1) * 64;
  const int wn   = (w >> 1) * 64;
  const int col0 = blockIdx.y * 128;

  if ((int)blockIdx.x >= 128) {
    // ---------------- Q path ----------------
    const int row0 = ((int)blockIdx.x - 128) * 128;
    floatx4 acc[4][4];
#pragma unroll
    for (int a = 0; a < 4; ++a)
#pragma unroll
      for (int b = 0; b < 4; ++b) acc[a][b] = (floatx4){0.f, 0.f, 0.f, 0.f};

    for (int k0 = 0; k0 < 512; k0 += 64) {
#pragma unroll
      for (int i = 0; i < 4; ++i) {
        int c = i * 256 + tid;
        int r = c >> 3, off = (c & 7) * 8;
        const float* xp = x + (size_t)(row0 + r) * 512 + k0 + off;
        float4 a = *(const float4*)xp, b2 = *(const float4*)(xp + 4);
        half8 hx;
        hx[0] = (_Float16)a.x;  hx[1] = (_Float16)a.y;
        hx[2] = (_Float16)a.z;  hx[3] = (_Float16)a.w;
        hx[4] = (_Float16)b2.x; hx[5] = (_Float16)b2.y;
        hx[6] = (_Float16)b2.z; hx[7] = (_Float16)b2.w;
        *(half8*)&Xs[r][off] = hx;
        *(half8*)&Ws1[r][off] = *(const half8*)(Whq + (size_t)(col0 + r) * 512 + k0 + off);
      }
      __syncthreads();
#pragma unroll
      for (int kc = 0; kc < 2; ++kc) {
        half8 af[4], bf[4];
#pragma unroll
        for (int mb = 0; mb < 4; ++mb)
          af[mb] = *(const half8*)&Xs[wm + mb * 16 + n16][kc * 32 + quad * 8];
#pragma unroll
        for (int nb = 0; nb < 4; ++nb)
          bf[nb] = *(const half8*)&Ws1[wn + nb * 16 + n16][kc * 32 + quad * 8];
#pragma unroll
        for (int mb = 0; mb < 4; ++mb)
#pragma unroll
          for (int nb = 0; nb < 4; ++nb)
            acc[mb][nb] = MFMA16(af[mb], bf[nb], acc[mb][nb]);
      }
      __syncthreads();
    }
#pragma unroll
    for (int mb = 0; mb < 4; ++mb)
#pragma unroll
      for (int nb = 0; nb < 4; ++nb)
#pragma unroll
        for (int r = 0; r < 4; ++r) {
          int row = row0 + wm + mb * 16 + quad * 4 + r;
          int col = col0 + wn + nb * 16 + n16;
          Qh[(size_t)row * 512 + col] =
              (_Float16)((acc[mb][nb][r] + bq[col]) * qscale);
        }
    return;
  }

  // ---------------- KV path ----------------
  const int row0 = (int)blockIdx.x * 128;
  floatx4 accK[4][4], accV[4][4];
#pragma unroll
  for (int a = 0; a < 4; ++a)
#pragma unroll
    for (int b = 0; b < 4; ++b) {
      accK[a][b] = (floatx4){0.f, 0.f, 0.f, 0.f};
      accV[a][b] = (floatx4){0.f, 0.f, 0.f, 0.f};
    }

  for (int k0 = 0; k0 < 512; k0 += 64) {
#pragma unroll
    for (int i = 0; i < 4; ++i) {
      int c = i * 256 + tid;
      int r = c >> 3, off = (c & 7) * 8;
      const float* xp = enc + (size_t)(row0 + r) * 512 + k0 + off;
      float4 a = *(const float4*)xp, b2 = *(const float4*)(xp + 4);
      half8 hx;
      hx[0] = (_Float16)a.x;  hx[1] = (_Float16)a.y;
      hx[2] = (_Float16)a.z;  hx[3] = (_Float16)a.w;
      hx[4] = (_Float16)b2.x; hx[5] = (_Float16)b2.y;
      hx[6] = (_Float16)b2.z; hx[7] = (_Float16)b2.w;
      *(half8*)&Xs[r][off] = hx;
      *(half8*)&Ws1[r][off] = *(const half8*)(Whk + (size_t)(col0 + r) * 512 + k0 + off);
      *(half8*)&Ws2[r][off] = *(const half8*)(Whv + (size_t)(col0 + r) * 512 + k0 + off);
    }
    __syncthreads();
#pragma unroll
    for (int kc = 0; kc < 2; ++kc) {
      half8 af[4], bkf[4], bvf[4];
#pragma unroll
      for (int mb = 0; mb < 4; ++mb)
        af[mb] = *(const half8*)&Xs[wm + mb * 16 + n16][kc * 32 + quad * 8];
#pragma unroll
      for (int nb = 0; nb < 4; ++nb) {
        bkf[nb] = *(const half8*)&Ws1[wn + nb * 16 + n16][kc * 32 + quad * 8];
        bvf[nb] = *(const half8*)&Ws2[wn + nb * 16 + n16][kc * 32 + quad * 8];
      }
#pragma unroll
      for (int mb = 0; mb < 4; ++mb)
#pragma unroll
        for (int nb = 0; nb < 4; ++nb) {
          accK[mb][nb] = MFMA16(af[mb], bkf[nb], accK[mb][nb]);
          accV[mb][nb] = MFMA16(af[mb], bvf[nb], accV[mb][nb]);
        }
    }
    __syncthreads();
  }

  // K epilogue: row-major f16
#pragma unroll
  for (int mb = 0; mb < 4; ++mb)
#pragma unroll
    for (int nb = 0; nb < 4; ++nb)
#pragma unroll
      for (int r = 0; r < 4; ++r) {
        int row = row0 + wm + mb * 16 + quad * 4 + r;
        int col = col0 + wn + nb * 16 + n16;
        Kh[(size_t)row * 512 + col] = (_Float16)(accK[mb][nb][r] + bk[col]);
      }

  // V epilogue: transpose through LDS (acc rows = kv, cols = d).
  _Float16 (*Ts)[144] = (_Float16(*)[144])SM;
#pragma unroll
  for (int mb = 0; mb < 4; ++mb)
#pragma unroll
    for (int nb = 0; nb < 4; ++nb) {
      int dl = wn + nb * 16 + n16;
      float bi = bv[col0 + dl];
      half4_t hv;
#pragma unroll
      for (int r = 0; r < 4; ++r) hv[r] = (_Float16)(accV[mb][nb][r] + bi);
      *(half4_t*)&Ts[dl][wm + mb * 16 + quad * 4] = hv;
    }
  __syncthreads();
  int b   = row0 >> 12;
  int kv0 = row0 & 4095;
#pragma unroll
  for (int i = 0; i < 8; ++i) {            // 128 d x 128 kv = 2048 half8 stores
    int f = i * 256 + tid;
    int dl = f >> 4, kv8 = (f & 15) * 8;
    half8 ov = *(const half8*)&Ts[dl][kv8];
    *(half8*)(Vt + (size_t)((b * 4 + blockIdx.y) * 128 + dl) * LKV_ + kv0 + kv8) = ov;
  }
}

// ---------------------------------------------------------------------------
// Flash attention, S^T form, split-KV x4. Block = 4 waves x 32 q = 128 q.
// LDS uses power-of-2 strides + XOR swizzle (SWZ) — the old +pad strides were
// ==4 (mod 32) dwords, aliasing 16-row fragment reads onto 8 bank groups
// (5.8M conflict cycles = ~16% of kernel). P aliases the K region (exact fit,
// 16 KB each); barrier after S-MFMAs protects cross-wave K reads.
// __launch_bounds__(256,2): (256,4) caused catastrophic VGPR spill (round 6).
// ---------------------------------------------------------------------------
__global__ __launch_bounds__(256, 2) void flash_mfma2(
    const _Float16* __restrict__ Qh,   // [B*LQ, 512], pre-scaled
    const _Float16* __restrict__ Kh,   // [B*LKV, 512]
    const _Float16* __restrict__ Vtg,  // [B*NH*HD, LKV], d-major
    _Float16* __restrict__ Opart,      // [64][1024][128] f16 unnormalized
    float* __restrict__ ml)            // [64][1024][2]
{
  __shared__ _Float16 U[64 * 128];     // 16,384 B: K tile (stride 128) | P alias
  __shared__ _Float16 Vs[128 * 64];    // 16,384 B: V tile d-major (stride 64)
  _Float16* Ks = U;                    // [64][128]
  _Float16* Ps = U;                    // [128][64] alias (rows = w*32+q)

  const int tid  = threadIdx.x;
  const int lane = tid & 63;
  const int w    = tid >> 6;
  const int n16  = lane & 15;
  const int quad = lane >> 4;

  const int xb    = blockIdx.x;        // bh*4 + split  (64)
  const int qt    = blockIdx.y;        // 0..7, 128 q each
  const int split = xb & 3;
  const int bh    = xb >> 2;
  const int h = bh & 3, b = bh >> 2;

  const _Float16* Qg = Qh + (size_t)(b * LQ_ + qt * 128) * DM + h * HD_;
  const _Float16* Kg = Kh + (size_t)(b * LKV_) * DM + h * HD_;
  const _Float16* Vg = Vtg + (size_t)(bh * HD_) * LKV_;

  // load Q frags for this wave (q = w*32 + qb*16 + n16) via 2 chunks through Ks
  half8 qf[2][4];
  const int chunk = w >> 1;
  const int qrb   = (w & 1) * 32;
#pragma unroll
  for (int c = 0; c < 2; ++c) {
#pragma unroll
    for (int i = 0; i < 4; ++i) {
      int f = i * 256 + tid;
      int r = f >> 4, c8 = (f & 15) * 8;
      *(half8*)&Ks[r * 128 + SWZ(c8, r)] =
          *(const half8*)(Qg + (size_t)(c * 64 + r) * DM + c8);
    }
    __syncthreads();
    if (chunk == c) {
#pragma unroll
      for (int qb = 0; qb < 2; ++qb) {
        int qr = qrb + qb * 16 + n16;
#pragma unroll
        for (int kc = 0; kc < 4; ++kc)
          qf[qb][kc] = *(const half8*)&Ks[qr * 128 + SWZ(kc * 32 + quad * 8, qr)];
      }
    }
    __syncthreads();
  }

  floatx4 o[2][8];
#pragma unroll
  for (int mb = 0; mb < 2; ++mb)
#pragma unroll
    for (int vb = 0; vb < 8; ++vb) o[mb][vb] = (floatx4){0.f, 0.f, 0.f, 0.f};
  float m_i[2] = {-INFINITY, -INFINITY};
  float l_i[2] = {0.f, 0.f};

  for (int kt = split * 16; kt < split * 16 + 16; ++kt) {
    // stage K (64 kv x 128 d) and V (128 d x 64 kv)
#pragma unroll
    for (int i = 0; i < 4; ++i) {
      int f = i * 256 + tid;
      int r = f >> 4, c8 = (f & 15) * 8;
      *(half8*)&Ks[r * 128 + SWZ(c8, r)] =
          *(const half8*)(Kg + (size_t)(kt * 64 + r) * DM + c8);
    }
#pragma unroll
    for (int i = 0; i < 4; ++i) {
      int f = i * 256 + tid;
      int d = f >> 3, kv8 = (f & 7) * 8;
      *(half8*)&Vs[d * 64 + SWZ(kv8, d)] =
          *(const half8*)(Vg + (size_t)d * LKV_ + kt * 64 + kv8);
    }
    __syncthreads();

    // S^T per wave: rows kv=cb*16+quad*4+r, col q=qb*16+n16
    floatx4 s[2][4];
#pragma unroll
    for (int qb = 0; qb < 2; ++qb)
#pragma unroll
      for (int cb = 0; cb < 4; ++cb) s[qb][cb] = (floatx4){0.f, 0.f, 0.f, 0.f};
#pragma unroll
    for (int cb = 0; cb < 4; ++cb) {
      int kr = cb * 16 + n16;
#pragma unroll
      for (int kc = 0; kc < 4; ++kc) {
        half8 kf = *(const half8*)&Ks[kr * 128 + SWZ(kc * 32 + quad * 8, kr)];
        s[0][cb] = MFMA16(kf, qf[0][kc], s[0][cb]);
        s[1][cb] = MFMA16(kf, qf[1][kc], s[1][cb]);
      }
    }
    __syncthreads();   // all waves done reading Ks before P (aliased) overwrites

    // online softmax per q column; reduce across quads (xor 16, 32)
    float alpha[2];
#pragma unroll
    for (int qb = 0; qb < 2; ++qb) {
      float mx = -INFINITY;
#pragma unroll
      for (int cb = 0; cb < 4; ++cb)
#pragma unroll
        for (int r = 0; r < 4; ++r) mx = fmaxf(mx, s[qb][cb][r]);
      mx = fmaxf(mx, __shfl_xor(mx, 16));
      mx = fmaxf(mx, __shfl_xor(mx, 32));
      float mn = fmaxf(m_i[qb], mx);
      alpha[qb] = __expf(m_i[qb] - mn);
      m_i[qb] = mn;
      float rs = 0.f;
      int pr = w * 32 + qb * 16 + n16;
#pragma unroll
      for (int cb = 0; cb < 4; ++cb) {
        half4_t ph;
#pragma unroll
        for (int r = 0; r < 4; ++r) {
          float p = __expf(s[qb][cb][r] - mn);
          rs += p;
          ph[r] = (_Float16)p;
        }
        *(half4_t*)&Ps[pr * 64 + SWZ(cb * 16 + quad * 4, pr)] = ph;
      }
      rs += __shfl_xor(rs, 16);
      rs += __shfl_xor(rs, 32);
      l_i[qb] = l_i[qb] * alpha[qb] + rs;
    }

    // rescale O only if some q-row saw a new max (wave-uniform vote)
    if (__ballot((alpha[0] != 1.f) || (alpha[1] != 1.f))) {
#pragma unroll
      for (int mb = 0; mb < 2; ++mb) {
#pragma unroll
        for (int r = 0; r < 4; ++r) {
          float a = __shfl(alpha[mb], (lane & 48) | (quad * 4 + r));
#pragma unroll
          for (int vb = 0; vb < 8; ++vb) o[mb][vb][r] *= a;
        }
      }
    }

    // O += P V  (P from per-wave LDS slice; intra-wave ordering)
    half8 pf[2][2];
#pragma unroll
    for (int mb = 0; mb < 2; ++mb) {
      int pr = w * 32 + mb * 16 + n16;
#pragma unroll
      for (int kc = 0; kc < 2; ++kc)
        pf[mb][kc] = *(const half8*)&Ps[pr * 64 + SWZ(kc * 32 + quad * 8, pr)];
    }
#pragma unroll
    for (int vb = 0; vb < 8; ++vb) {
      int vr = vb * 16 + n16;
#pragma unroll
      for (int kc = 0; kc < 2; ++kc) {
        half8 vf = *(const half8*)&Vs[vr * 64 + SWZ(kc * 32 + quad * 8, vr)];
        o[0][vb] = MFMA16(pf[0][kc], vf, o[0][vb]);
        o[1][vb] = MFMA16(pf[1][kc], vf, o[1][vb]);
      }
    }
    __syncthreads();   // P (and Vs) free before next stage
  }

  // write unnormalized partial O (f16) and (m,l)
  _Float16* Og = Opart + ((size_t)xb * 1024 + qt * 128 + w * 32) * HD_;
#pragma unroll
  for (int mb = 0; mb < 2; ++mb)
#pragma unroll
    for (int r = 0; r < 4; ++r)
#pragma unroll
      for (int vb = 0; vb < 8; ++vb)
        Og[(size_t)(mb * 16 + quad * 4 + r) * HD_ + vb * 16 + n16] =
            (_Float16)o[mb][vb][r];
  if (quad == 0) {
#pragma unroll
    for (int qb = 0; qb < 2; ++qb) {
      size_t qi = (size_t)xb * 1024 + qt * 128 + w * 32 + qb * 16 + n16;
      ml[qi * 2] = m_i[qb];
      ml[qi * 2 + 1] = l_i[qb];
    }
  }
}

// ---------------------------------------------------------------------------
// Output projection with FUSED split-combine:
//   out[4096,512] f32 = combine(Opart, ml) @ Who^T + bo
// Tile 64x128, grid (64,4) = 256 blocks (fills all CUs; old 128-block grid
// left half the GPU idle, and the separate combine kernel + 8 MB CTX
// round-trip are eliminated).
// ---------------------------------------------------------------------------
__global__ __launch_bounds__(256) void proj_out_fused(
    const _Float16* __restrict__ Opart,   // [64][1024][128]
    const float* __restrict__ ml,         // [64][1024][2]
    const _Float16* __restrict__ Who,
    const float* __restrict__ bo,
    float* __restrict__ Y)
{
  __shared__ _Float16 Xs[64][72];
  __shared__ _Float16 Ws[128][72];
  __shared__ float CW[4][64][8];    // [h][row][0..3]=wgt_p, [4]=1/L

  const int tid  = threadIdx.x;
  const int lane = tid & 63;
  const int w    = tid >> 6;
  const int n16  = lane & 15;
  const int quad = lane >> 4;
  const int wm   = (w & 1) * 32;
  const int wn   = (w >> 1) * 64;
  const int row0 = blockIdx.x * 64;
  const int col0 = blockIdx.y * 128;
  const int b    = row0 >> 10;       // uniform (64 | 1024)

  // precompute combine weights for all (h, row) of this block
  {
    int h = tid >> 6, r = tid & 63;
    int q = (row0 + r) & 1023;
    int bh = b * 4 + h;
    float m[4], l[4], M = -INFINITY;
#pragma unroll
    for (int p = 0; p < 4; ++p) {
      size_t idx = ((size_t)(bh * 4 + p) * 1024 + q) * 2;
      m[p] = ml[idx]; l[p] = ml[idx + 1];
      M = fmaxf(M, m[p]);
    }
    float L = 0.f, wts[4];
#pragma unroll
    for (int p = 0; p < 4; ++p) { wts[p] = __expf(m[p] - M); L += wts[p] * l[p]; }
    float inv = 1.f / L;
#pragma unroll
    for (int p = 0; p < 4; ++p) CW[h][r][p] = wts[p] * inv;
    CW[h][r][4] = 0.f;  // unused
  }
  __syncthreads();

  floatx4 acc[2][4];
#pragma unroll
  for (int a = 0; a < 2; ++a)
#pragma unroll
    for (int c = 0; c < 4; ++c) acc[a][c] = (floatx4){0.f, 0.f, 0.f, 0.f};

  for (int k0 = 0; k0 < 512; k0 += 64) {
    int h = k0 >> 7, d0 = k0 & 127;
    int bh = b * 4 + h;
    // stage X: combine 4 partials inline -> f16 tile [64 rows x 64 cols]
#pragma unroll
    for (int i = 0; i < 2; ++i) {
      int f = i * 256 + tid;
      int r = f >> 3, c8 = (f & 7) * 8;
      int q = (row0 + r) & 1023;
      float w0 = CW[h][r][0], w1 = CW[h][r][1];
      float w2 = CW[h][r][2], w3 = CW[h][r][3];
      size_t base = ((size_t)(bh * 4) * 1024 + q) * 128 + d0 + c8;
      half8 v0 = *(const half8*)(Opart + base);
      half8 v1 = *(const half8*)(Opart + base + 131072);
      half8 v2 = *(const half8*)(Opart + base + 262144);
      half8 v3 = *(const half8*)(Opart + base + 393216);
      half8 hx;
#pragma unroll
      for (int j = 0; j < 8; ++j)
        hx[j] = (_Float16)(w0 * (float)v0[j] + w1 * (float)v1[j] +
                           w2 * (float)v2[j] + w3 * (float)v3[j]);
      *(half8*)&Xs[r][c8] = hx;
    }
    // stage W: [128 out-cols x 64 k]
#pragma unroll
    for (int i = 0; i < 4; ++i) {
      int f = i * 256 + tid;
      int r = f >> 3, c8 = (f & 7) * 8;
      *(half8*)&Ws[r][c8] = *(const half8*)(Who + (size_t)(col0 + r) * 512 + k0 + c8);
    }
    __syncthreads();
#pragma unroll
    for (int kc = 0; kc < 2; ++kc) {
      half8 af[2], bf[4];
#pragma unroll
      for (int mb = 0; mb < 2; ++mb)
        af[mb] = *(const half8*)&Xs[wm + mb * 16 + n16][kc * 32 + quad * 8];
#pragma unroll
      for (int nb = 0; nb < 4; ++nb)
        bf[nb] = *(const half8*)&Ws[wn + nb * 16 + n16][kc * 32 + quad * 8];
#pragma unroll
      for (int mb = 0; mb < 2; ++mb)
#pragma unroll
        for (int nb = 0; nb < 4; ++nb)
          acc[mb][nb] = MFMA16(af[mb], bf[nb], acc[mb][nb]);
    }
    __syncthreads();
  }

#pragma unroll
  for (int mb = 0; mb < 2; ++mb)
#pragma unroll
    for (int nb = 0; nb < 4; ++nb)
#pragma unroll
      for (int r = 0; r < 4; ++r) {
        int row = row0 + wm + mb * 16 + quad * 4 + r;
        int col = col0 + wn + nb * 16 + n16;
        Y[(size_t)row * 512 + col] = acc[mb][nb][r] + bo[col];
      }
}

// ---------------------------------------------------------------------------
extern "C" void kernel_launch(void* const* d_in, const int* in_sizes, int n_in,
                              void* d_out, int out_size, void* d_ws, size_t ws_size,
                              hipStream_t stream) {
  const float* x   = (const float*)d_in[0];
  const float* enc = (const float*)d_in[1];
  const float* Wq  = (const float*)d_in[2];
  const float* Wk  = (const float*)d_in[3];
  const float* Wv  = (const float*)d_in[4];
  const float* bq  = (const float*)d_in[5];
  const float* bk  = (const float*)d_in[6];
  const float* bv  = (const float*)d_in[7];
  const float* Wo  = (const float*)d_in[8];
  const float* bo  = (const float*)d_in[9];
  float* out = (float*)d_out;

  // workspace layout (MB offsets):
  //   0  Qh    f16 [4096 x 512]         4 MB
  //   4  Kh    f16 [16384 x 512]       16 MB
  //  20  Vtg   f16 [2048 x 4096]       16 MB
  //  36  Opart f16 [64 x 1024 x 128]   16 MB
  //  52  ml    f32 [64 x 1024 x 2]     0.5 MB
  //  53  Wh    f16 [4 x 512 x 512]      2 MB     (total 55 MB)
  char* ws = (char*)d_ws;
  _Float16* Qh    = (_Float16*)(ws);
  _Float16* Kh    = (_Float16*)(ws + (4u  << 20));
  _Float16* Vtg   = (_Float16*)(ws + (20u << 20));
  _Float16* Opart = (_Float16*)(ws + (36u << 20));
  float*    mlp   = (float*)   (ws + (52u << 20));
  _Float16* Wh    = (_Float16*)(ws + (53u << 20));

  _Float16* Whq = Wh;
  _Float16* Whk = Wh + 262144;
  _Float16* Whv = Wh + 524288;
  _Float16* Who = Wh + 786432;

  const float qscale = 0.08838834764831845f;  // 1/sqrt(128)
  dim3 blk(256);

  prep_w<<<dim3(1024), blk, 0, stream>>>(Wq, Wk, Wv, Wo, Wh);

  proj_qkv<<<dim3(160, 4), blk, 0, stream>>>(
      x, enc, Whq, Whk, Whv, bq, bk, bv, Qh, Kh, Vtg, qscale);

  flash_mfma2<<<dim3(64, 8), blk, 0, stream>>>(Qh, Kh, Vtg, Opart, mlp);

  proj_out_fused<<<dim3(64, 4), blk, 0, stream>>>(Opart, mlp, Who, bo, out);
}

// Round 10
// 193.483 us; speedup vs baseline: 1.0637x; 1.0637x over previous
//
#include <hip/hip_runtime.h>
#include <math.h>

// Problem constants
#define B_    4
#define LQ_   1024
#define LKV_  4096
#define DM    512    // model dim
#define NH    4
#define HD_   128    // head dim

typedef _Float16 half8   __attribute__((ext_vector_type(8)));
typedef _Float16 half4_t __attribute__((ext_vector_type(4)));
typedef float    floatx4 __attribute__((ext_vector_type(4)));

#define MFMA16(a, b, c) __builtin_amdgcn_mfma_f32_16x16x32_f16((a), (b), (c), 0, 0, 0)

// XOR swizzle: power-of-2 row strides + per-row column xor keeps 16B alignment
// and spreads 16-row fragment reads across all 32 banks (<=2-way, free).
#define SWZ(c, r) ((c) ^ (((r) & 7) << 3))

// ---------------------------------------------------------------------------
// prep: cast the 4 weight matrices to f16.
// ---------------------------------------------------------------------------
__global__ __launch_bounds__(256) void prep_w(
    const float* __restrict__ Wq, const float* __restrict__ Wk,
    const float* __restrict__ Wv, const float* __restrict__ Wo,
    _Float16* __restrict__ Wh)
{
  int i = blockIdx.x * 256 + threadIdx.x;   // 0..262143
  int wsel = i >> 16;                       // 65536 float4 per W
  const float* src = (wsel == 0) ? Wq : (wsel == 1) ? Wk : (wsel == 2) ? Wv : Wo;
  size_t off = i & 65535;
  float4 v = *(const float4*)(src + off * 4);
  half4_t h;
  h[0] = (_Float16)v.x; h[1] = (_Float16)v.y;
  h[2] = (_Float16)v.z; h[3] = (_Float16)v.w;
  *(half4_t*)(Wh + ((size_t)wsel << 18) + off * 4) = h;
}

// ---------------------------------------------------------------------------
// Fused Q+K+V projection. Grid (160, 4). Swizzled stride-64 LDS: 48 KB
// -> 3 blocks/CU (was 55 KB / 2 blocks), conflict-free fragment reads.
//   bx <  128 : KV path — dual GEMM vs enc rows [bx*128, +128):
//               K row-major f16, V transposed per-head to Vt.
//   bx >= 128 : Q path  — GEMM vs x rows [(bx-128)*128, +128), f16 out *qscale.
// ---------------------------------------------------------------------------
__global__ __launch_bounds__(256, 2) void proj_qkv(
    const float* __restrict__ x,       // [4096, 512] f32
    const float* __restrict__ enc,     // [16384, 512] f32
    const _Float16* __restrict__ Whq,
    const _Float16* __restrict__ Whk,
    const _Float16* __restrict__ Whv,
    const float* __restrict__ bq,
    const float* __restrict__ bk,
    const float* __restrict__ bv,
    _Float16* __restrict__ Qh,
    _Float16* __restrict__ Kh,
    _Float16* __restrict__ Vt,
    float qscale)
{
  __shared__ _Float16 SM[3 * 128 * 64];          // 49,152 B
  _Float16* Xs  = SM;                 // [128][64] swizzled
  _Float16* Ws1 = SM + 128 * 64;
  _Float16* Ws2 = SM + 2 * 128 * 64;

  const int tid  = threadIdx.x;
  const int lane = tid & 63;
  const int w    = tid >> 6;
  const int n16  = lane & 15;
  const int quad = lane >> 4;
  const int wm   = (w & 1) * 64;
  const int wn   = (w >> 1) * 64;
  const int col0 = blockIdx.y * 128;

  if ((int)blockIdx.x >= 128) {
    // ---------------- Q path ----------------
    const int row0 = ((int)blockIdx.x - 128) * 128;
    floatx4 acc[4][4];
#pragma unroll
    for (int a = 0; a < 4; ++a)
#pragma unroll
      for (int b = 0; b < 4; ++b) acc[a][b] = (floatx4){0.f, 0.f, 0.f, 0.f};

    for (int k0 = 0; k0 < 512; k0 += 64) {
#pragma unroll
      for (int i = 0; i < 4; ++i) {
        int c = i * 256 + tid;
        int r = c >> 3, off = (c & 7) * 8;
        const float* xp = x + (size_t)(row0 + r) * 512 + k0 + off;
        float4 a = *(const float4*)xp, b2 = *(const float4*)(xp + 4);
        half8 hx;
        hx[0] = (_Float16)a.x;  hx[1] = (_Float16)a.y;
        hx[2] = (_Float16)a.z;  hx[3] = (_Float16)a.w;
        hx[4] = (_Float16)b2.x; hx[5] = (_Float16)b2.y;
        hx[6] = (_Float16)b2.z; hx[7] = (_Float16)b2.w;
        *(half8*)&Xs[r * 64 + SWZ(off, r)] = hx;
        *(half8*)&Ws1[r * 64 + SWZ(off, r)] =
            *(const half8*)(Whq + (size_t)(col0 + r) * 512 + k0 + off);
      }
      __syncthreads();
#pragma unroll
      for (int kc = 0; kc < 2; ++kc) {
        half8 af[4], bf[4];
#pragma unroll
        for (int mb = 0; mb < 4; ++mb) {
          int r = wm + mb * 16 + n16;
          af[mb] = *(const half8*)&Xs[r * 64 + SWZ(kc * 32 + quad * 8, r)];
        }
#pragma unroll
        for (int nb = 0; nb < 4; ++nb) {
          int r = wn + nb * 16 + n16;
          bf[nb] = *(const half8*)&Ws1[r * 64 + SWZ(kc * 32 + quad * 8, r)];
        }
#pragma unroll
        for (int mb = 0; mb < 4; ++mb)
#pragma unroll
          for (int nb = 0; nb < 4; ++nb)
            acc[mb][nb] = MFMA16(af[mb], bf[nb], acc[mb][nb]);
      }
      __syncthreads();
    }
#pragma unroll
    for (int mb = 0; mb < 4; ++mb)
#pragma unroll
      for (int nb = 0; nb < 4; ++nb)
#pragma unroll
        for (int r = 0; r < 4; ++r) {
          int row = row0 + wm + mb * 16 + quad * 4 + r;
          int col = col0 + wn + nb * 16 + n16;
          Qh[(size_t)row * 512 + col] =
              (_Float16)((acc[mb][nb][r] + bq[col]) * qscale);
        }
    return;
  }

  // ---------------- KV path ----------------
  const int row0 = (int)blockIdx.x * 128;
  floatx4 accK[4][4], accV[4][4];
#pragma unroll
  for (int a = 0; a < 4; ++a)
#pragma unroll
    for (int b = 0; b < 4; ++b) {
      accK[a][b] = (floatx4){0.f, 0.f, 0.f, 0.f};
      accV[a][b] = (floatx4){0.f, 0.f, 0.f, 0.f};
    }

  for (int k0 = 0; k0 < 512; k0 += 64) {
#pragma unroll
    for (int i = 0; i < 4; ++i) {
      int c = i * 256 + tid;
      int r = c >> 3, off = (c & 7) * 8;
      const float* xp = enc + (size_t)(row0 + r) * 512 + k0 + off;
      float4 a = *(const float4*)xp, b2 = *(const float4*)(xp + 4);
      half8 hx;
      hx[0] = (_Float16)a.x;  hx[1] = (_Float16)a.y;
      hx[2] = (_Float16)a.z;  hx[3] = (_Float16)a.w;
      hx[4] = (_Float16)b2.x; hx[5] = (_Float16)b2.y;
      hx[6] = (_Float16)b2.z; hx[7] = (_Float16)b2.w;
      *(half8*)&Xs[r * 64 + SWZ(off, r)] = hx;
      *(half8*)&Ws1[r * 64 + SWZ(off, r)] =
          *(const half8*)(Whk + (size_t)(col0 + r) * 512 + k0 + off);
      *(half8*)&Ws2[r * 64 + SWZ(off, r)] =
          *(const half8*)(Whv + (size_t)(col0 + r) * 512 + k0 + off);
    }
    __syncthreads();
#pragma unroll
    for (int kc = 0; kc < 2; ++kc) {
      half8 af[4], bkf[4], bvf[4];
#pragma unroll
      for (int mb = 0; mb < 4; ++mb) {
        int r = wm + mb * 16 + n16;
        af[mb] = *(const half8*)&Xs[r * 64 + SWZ(kc * 32 + quad * 8, r)];
      }
#pragma unroll
      for (int nb = 0; nb < 4; ++nb) {
        int r = wn + nb * 16 + n16;
        bkf[nb] = *(const half8*)&Ws1[r * 64 + SWZ(kc * 32 + quad * 8, r)];
        bvf[nb] = *(const half8*)&Ws2[r * 64 + SWZ(kc * 32 + quad * 8, r)];
      }
#pragma unroll
      for (int mb = 0; mb < 4; ++mb)
#pragma unroll
        for (int nb = 0; nb < 4; ++nb) {
          accK[mb][nb] = MFMA16(af[mb], bkf[nb], accK[mb][nb]);
          accV[mb][nb] = MFMA16(af[mb], bvf[nb], accV[mb][nb]);
        }
    }
    __syncthreads();
  }

  // K epilogue: row-major f16
#pragma unroll
  for (int mb = 0; mb < 4; ++mb)
#pragma unroll
    for (int nb = 0; nb < 4; ++nb)
#pragma unroll
      for (int r = 0; r < 4; ++r) {
        int row = row0 + wm + mb * 16 + quad * 4 + r;
        int col = col0 + wn + nb * 16 + n16;
        Kh[(size_t)row * 512 + col] = (_Float16)(accK[mb][nb][r] + bk[col]);
      }

  // V epilogue: transpose through LDS (acc rows = kv, cols = d).
  _Float16 (*Ts)[144] = (_Float16(*)[144])SM;    // 36,864 B <= 49,152 B
#pragma unroll
  for (int mb = 0; mb < 4; ++mb)
#pragma unroll
    for (int nb = 0; nb < 4; ++nb) {
      int dl = wn + nb * 16 + n16;
      float bi = bv[col0 + dl];
      half4_t hv;
#pragma unroll
      for (int r = 0; r < 4; ++r) hv[r] = (_Float16)(accV[mb][nb][r] + bi);
      *(half4_t*)&Ts[dl][wm + mb * 16 + quad * 4] = hv;
    }
  __syncthreads();
  int b   = row0 >> 12;
  int kv0 = row0 & 4095;
#pragma unroll
  for (int i = 0; i < 8; ++i) {            // 128 d x 128 kv = 2048 half8 stores
    int f = i * 256 + tid;
    int dl = f >> 4, kv8 = (f & 15) * 8;
    half8 ov = *(const half8*)&Ts[dl][kv8];
    *(half8*)(Vt + (size_t)((b * 4 + blockIdx.y) * 128 + dl) * LKV_ + kv0 + kv8) = ov;
  }
}

// ---------------------------------------------------------------------------
// Flash attention, S^T + O^T form, split-KV x4. Block = 4 waves x 32 q.
// S^T = K Q^T (C/D: row=kv, col=q) -> b64 P stores, per-q-column softmax.
// O^T = V^T P^T: A=V^T-frag and B=P^T-frag are IDENTICAL LDS reads to the
// O-form's vf/pf (A[m][k] of P and B[k][n] of P^T read the same row), but
// C/D rows become d and cols become q=n16 -> alpha is per-lane (no shuffle
// broadcast) and the epilogue packs half4 along d (LDS bounce -> b128 global).
// P aliases the K region; barrier after S-MFMAs protects cross-wave K reads.
// __launch_bounds__(256,2): (256,4) caused catastrophic VGPR spill (round 6).
// ---------------------------------------------------------------------------
__global__ __launch_bounds__(256, 2) void flash_mfma2(
    const _Float16* __restrict__ Qh,   // [B*LQ, 512], pre-scaled
    const _Float16* __restrict__ Kh,   // [B*LKV, 512]
    const _Float16* __restrict__ Vtg,  // [B*NH*HD, LKV], d-major
    _Float16* __restrict__ Opart,      // [64][1024][128] f16 unnormalized
    float* __restrict__ ml)            // [64][1024][2]
{
  __shared__ _Float16 SH[2 * 64 * 128];  // 32 KB total
  _Float16* Ks = SH;                     // [64][128] swizzled | P alias | O bounce
  _Float16* Ps = SH;                     // [128][64] swizzled (rows = w*32+q)
  _Float16* Vs = SH + 64 * 128;          // [128][64] swizzled, d-major

  const int tid  = threadIdx.x;
  const int lane = tid & 63;
  const int w    = tid >> 6;
  const int n16  = lane & 15;
  const int quad = lane >> 4;

  const int xb    = blockIdx.x;        // bh*4 + split  (64)
  const int qt    = blockIdx.y;        // 0..7, 128 q each
  const int split = xb & 3;
  const int bh    = xb >> 2;
  const int h = bh & 3, b = bh >> 2;

  const _Float16* Qg = Qh + (size_t)(b * LQ_ + qt * 128) * DM + h * HD_;
  const _Float16* Kg = Kh + (size_t)(b * LKV_) * DM + h * HD_;
  const _Float16* Vg = Vtg + (size_t)(bh * HD_) * LKV_;

  // load Q frags for this wave (q = w*32 + qb*16 + n16) via 2 chunks through Ks
  half8 qf[2][4];
  const int chunk = w >> 1;
  const int qrb   = (w & 1) * 32;
#pragma unroll
  for (int c = 0; c < 2; ++c) {
#pragma unroll
    for (int i = 0; i < 4; ++i) {
      int f = i * 256 + tid;
      int r = f >> 4, c8 = (f & 15) * 8;
      *(half8*)&Ks[r * 128 + SWZ(c8, r)] =
          *(const half8*)(Qg + (size_t)(c * 64 + r) * DM + c8);
    }
    __syncthreads();
    if (chunk == c) {
#pragma unroll
      for (int qb = 0; qb < 2; ++qb) {
        int qr = qrb + qb * 16 + n16;
#pragma unroll
        for (int kc = 0; kc < 4; ++kc)
          qf[qb][kc] = *(const half8*)&Ks[qr * 128 + SWZ(kc * 32 + quad * 8, qr)];
      }
    }
    __syncthreads();
  }

  floatx4 oT[2][8];                    // [qb][vb]: rows d=vb*16+quad*4+r, col q=qb*16+n16
#pragma unroll
  for (int qb = 0; qb < 2; ++qb)
#pragma unroll
    for (int vb = 0; vb < 8; ++vb) oT[qb][vb] = (floatx4){0.f, 0.f, 0.f, 0.f};
  float m_i[2] = {-INFINITY, -INFINITY};
  float l_i[2] = {0.f, 0.f};

  for (int kt = split * 16; kt < split * 16 + 16; ++kt) {
    // stage K (64 kv x 128 d) and V (128 d x 64 kv)
#pragma unroll
    for (int i = 0; i < 4; ++i) {
      int f = i * 256 + tid;
      int r = f >> 4, c8 = (f & 15) * 8;
      *(half8*)&Ks[r * 128 + SWZ(c8, r)] =
          *(const half8*)(Kg + (size_t)(kt * 64 + r) * DM + c8);
    }
#pragma unroll
    for (int i = 0; i < 4; ++i) {
      int f = i * 256 + tid;
      int d = f >> 3, kv8 = (f & 7) * 8;
      *(half8*)&Vs[d * 64 + SWZ(kv8, d)] =
          *(const half8*)(Vg + (size_t)d * LKV_ + kt * 64 + kv8);
    }
    __syncthreads();

    // S^T per wave: rows kv=cb*16+quad*4+r, col q=qb*16+n16
    floatx4 s[2][4];
#pragma unroll
    for (int qb = 0; qb < 2; ++qb)
#pragma unroll
      for (int cb = 0; cb < 4; ++cb) s[qb][cb] = (floatx4){0.f, 0.f, 0.f, 0.f};
#pragma unroll
    for (int cb = 0; cb < 4; ++cb) {
      int kr = cb * 16 + n16;
#pragma unroll
      for (int kc = 0; kc < 4; ++kc) {
        half8 kf = *(const half8*)&Ks[kr * 128 + SWZ(kc * 32 + quad * 8, kr)];
        s[0][cb] = MFMA16(kf, qf[0][kc], s[0][cb]);
        s[1][cb] = MFMA16(kf, qf[1][kc], s[1][cb]);
      }
    }
    __syncthreads();   // all waves done reading Ks before P (aliased) overwrites

    // online softmax per q column; reduce across quads (xor 16, 32)
    float alpha[2];
#pragma unroll
    for (int qb = 0; qb < 2; ++qb) {
      float mx = -INFINITY;
#pragma unroll
      for (int cb = 0; cb < 4; ++cb)
#pragma unroll
        for (int r = 0; r < 4; ++r) mx = fmaxf(mx, s[qb][cb][r]);
      mx = fmaxf(mx, __shfl_xor(mx, 16));
      mx = fmaxf(mx, __shfl_xor(mx, 32));
      float mn = fmaxf(m_i[qb], mx);
      alpha[qb] = __expf(m_i[qb] - mn);
      m_i[qb] = mn;
      float rs = 0.f;
      int pr = w * 32 + qb * 16 + n16;
#pragma unroll
      for (int cb = 0; cb < 4; ++cb) {
        half4_t ph;
#pragma unroll
        for (int r = 0; r < 4; ++r) {
          float p = __expf(s[qb][cb][r] - mn);
          rs += p;
          ph[r] = (_Float16)p;
        }
        *(half4_t*)&Ps[pr * 64 + SWZ(cb * 16 + quad * 4, pr)] = ph;
      }
      rs += __shfl_xor(rs, 16);
      rs += __shfl_xor(rs, 32);
      l_i[qb] = l_i[qb] * alpha[qb] + rs;
    }

    // rescale O^T: alpha is per-lane for col q=n16 (no broadcast needed)
    if (__ballot((alpha[0] != 1.f) || (alpha[1] != 1.f))) {
#pragma unroll
      for (int qb = 0; qb < 2; ++qb)
#pragma unroll
        for (int vb = 0; vb < 8; ++vb)
          oT[qb][vb] *= alpha[qb];
    }

    // O^T += V^T P^T  (identical LDS reads to the O-form; operands swapped)
    half8 pf[2][2];
#pragma unroll
    for (int qb = 0; qb < 2; ++qb) {
      int pr = w * 32 + qb * 16 + n16;
#pragma unroll
      for (int kc = 0; kc < 2; ++kc)
        pf[qb][kc] = *(const half8*)&Ps[pr * 64 + SWZ(kc * 32 + quad * 8, pr)];
    }
#pragma unroll
    for (int vb = 0; vb < 8; ++vb) {
      int vr = vb * 16 + n16;
#pragma unroll
      for (int kc = 0; kc < 2; ++kc) {
        half8 vf = *(const half8*)&Vs[vr * 64 + SWZ(kc * 32 + quad * 8, vr)];
        oT[0][vb] = MFMA16(vf, pf[0][kc], oT[0][vb]);
        oT[1][vb] = MFMA16(vf, pf[1][kc], oT[1][vb]);
      }
    }
    __syncthreads();   // P (and Vs) free before next stage
  }

  // epilogue: bounce O^T tile through LDS (as [q][d], swizzled) -> b128 stores
  _Float16* Os = SH;                   // [128][128] swizzled, 32 KB
#pragma unroll
  for (int qb = 0; qb < 2; ++qb) {
    int q = w * 32 + qb * 16 + n16;
#pragma unroll
    for (int vb = 0; vb < 8; ++vb) {
      half4_t hv;
#pragma unroll
      for (int r = 0; r < 4; ++r) hv[r] = (_Float16)oT[qb][vb][r];
      *(half4_t*)&Os[q * 128 + SWZ(vb * 16 + quad * 4, q)] = hv;
    }
  }
  __syncthreads();
  _Float16* Og = Opart + ((size_t)xb * 1024 + qt * 128) * HD_;
#pragma unroll
  for (int i = 0; i < 8; ++i) {
    int f = i * 256 + tid;
    int q = f >> 4, c8 = (f & 15) * 8;
    *(half8*)(Og + (size_t)q * HD_ + c8) = *(const half8*)&Os[q * 128 + SWZ(c8, q)];
  }
  if (quad == 0) {
#pragma unroll
    for (int qb = 0; qb < 2; ++qb) {
      size_t qi = (size_t)xb * 1024 + qt * 128 + w * 32 + qb * 16 + n16;
      ml[qi * 2] = m_i[qb];
      ml[qi * 2 + 1] = l_i[qb];
    }
  }
}

// ---------------------------------------------------------------------------
// Output projection with FUSED split-combine (swizzled stride-64 LDS):
//   out[4096,512] f32 = combine(Opart, ml) @ Who^T + bo
// Tile 64x128, grid (64,4) = 256 blocks.
// ---------------------------------------------------------------------------
__global__ __launch_bounds__(256) void proj_out_fused(
    const _Float16* __restrict__ Opart,   // [64][1024][128]
    const float* __restrict__ ml,         // [64][1024][2]
    const _Float16* __restrict__ Who,
    const float* __restrict__ bo,
    float* __restrict__ Y)
{
  __shared__ _Float16 Xs[64 * 64];
  __shared__ _Float16 Ws[128 * 64];
  __shared__ float CW[4][64][8];    // [h][row][0..3] = wgt_p / L

  const int tid  = threadIdx.x;
  const int lane = tid & 63;
  const int w    = tid >> 6;
  const int n16  = lane & 15;
  const int quad = lane >> 4;
  const int wm   = (w & 1) * 32;
  const int wn   = (w >> 1) * 64;
  const int row0 = blockIdx.x * 64;
  const int col0 = blockIdx.y * 128;
  const int b    = row0 >> 10;

  // precompute combine weights for all (h, row) of this block
  {
    int h = tid >> 6, r = tid & 63;
    int q = (row0 + r) & 1023;
    int bh = b * 4 + h;
    float m[4], l[4], M = -INFINITY;
#pragma unroll
    for (int p = 0; p < 4; ++p) {
      size_t idx = ((size_t)(bh * 4 + p) * 1024 + q) * 2;
      m[p] = ml[idx]; l[p] = ml[idx + 1];
      M = fmaxf(M, m[p]);
    }
    float L = 0.f, wts[4];
#pragma unroll
    for (int p = 0; p < 4; ++p) { wts[p] = __expf(m[p] - M); L += wts[p] * l[p]; }
    float inv = 1.f / L;
#pragma unroll
    for (int p = 0; p < 4; ++p) CW[h][r][p] = wts[p] * inv;
  }
  __syncthreads();

  floatx4 acc[2][4];
#pragma unroll
  for (int a = 0; a < 2; ++a)
#pragma unroll
    for (int c = 0; c < 4; ++c) acc[a][c] = (floatx4){0.f, 0.f, 0.f, 0.f};

  for (int k0 = 0; k0 < 512; k0 += 64) {
    int h = k0 >> 7, d0 = k0 & 127;
    int bh = b * 4 + h;
    // stage X: combine 4 partials inline -> f16 tile [64 rows x 64 cols]
#pragma unroll
    for (int i = 0; i < 2; ++i) {
      int f = i * 256 + tid;
      int r = f >> 3, c8 = (f & 7) * 8;
      int q = (row0 + r) & 1023;
      float w0 = CW[h][r][0], w1 = CW[h][r][1];
      float w2 = CW[h][r][2], w3 = CW[h][r][3];
      size_t base = ((size_t)(bh * 4) * 1024 + q) * 128 + d0 + c8;
      half8 v0 = *(const half8*)(Opart + base);
      half8 v1 = *(const half8*)(Opart + base + 131072);
      half8 v2 = *(const half8*)(Opart + base + 262144);
      half8 v3 = *(const half8*)(Opart + base + 393216);
      half8 hx;
#pragma unroll
      for (int j = 0; j < 8; ++j)
        hx[j] = (_Float16)(w0 * (float)v0[j] + w1 * (float)v1[j] +
                           w2 * (float)v2[j] + w3 * (float)v3[j]);
      *(half8*)&Xs[r * 64 + SWZ(c8, r)] = hx;
    }
    // stage W: [128 out-cols x 64 k]
#pragma unroll
    for (int i = 0; i < 4; ++i) {
      int f = i * 256 + tid;
      int r = f >> 3, c8 = (f & 7) * 8;
      *(half8*)&Ws[r * 64 + SWZ(c8, r)] =
          *(const half8*)(Who + (size_t)(col0 + r) * 512 + k0 + c8);
    }
    __syncthreads();
#pragma unroll
    for (int kc = 0; kc < 2; ++kc) {
      half8 af[2], bf[4];
#pragma unroll
      for (int mb = 0; mb < 2; ++mb) {
        int r = wm + mb * 16 + n16;
        af[mb] = *(const half8*)&Xs[r * 64 + SWZ(kc * 32 + quad * 8, r)];
      }
#pragma unroll
      for (int nb = 0; nb < 4; ++nb) {
        int r = wn + nb * 16 + n16;
        bf[nb] = *(const half8*)&Ws[r * 64 + SWZ(kc * 32 + quad * 8, r)];
      }
#pragma unroll
      for (int mb = 0; mb < 2; ++mb)
#pragma unroll
        for (int nb = 0; nb < 4; ++nb)
          acc[mb][nb] = MFMA16(af[mb], bf[nb], acc[mb][nb]);
    }
    __syncthreads();
  }

#pragma unroll
  for (int mb = 0; mb < 2; ++mb)
#pragma unroll
    for (int nb = 0; nb < 4; ++nb)
#pragma unroll
      for (int r = 0; r < 4; ++r) {
        int row = row0 + wm + mb * 16 + quad * 4 + r;
        int col = col0 + wn + nb * 16 + n16;
        Y[(size_t)row * 512 + col] = acc[mb][nb][r] + bo[col];
      }
}

// ---------------------------------------------------------------------------
extern "C" void kernel_launch(void* const* d_in, const int* in_sizes, int n_in,
                              void* d_out, int out_size, void* d_ws, size_t ws_size,
                              hipStream_t stream) {
  const float* x   = (const float*)d_in[0];
  const float* enc = (const float*)d_in[1];
  const float* Wq  = (const float*)d_in[2];
  const float* Wk  = (const float*)d_in[3];
  const float* Wv  = (const float*)d_in[4];
  const float* bq  = (const float*)d_in[5];
  const float* bk  = (const float*)d_in[6];
  const float* bv  = (const float*)d_in[7];
  const float* Wo  = (const float*)d_in[8];
  const float* bo  = (const float*)d_in[9];
  float* out = (float*)d_out;

  // workspace layout (MB offsets):
  //   0  Qh    f16 [4096 x 512]         4 MB
  //   4  Kh    f16 [16384 x 512]       16 MB
  //  20  Vtg   f16 [2048 x 4096]       16 MB
  //  36  Opart f16 [64 x 1024 x 128]   16 MB
  //  52  ml    f32 [64 x 1024 x 2]     0.5 MB
  //  53  Wh    f16 [4 x 512 x 512]      2 MB     (total 55 MB)
  char* ws = (char*)d_ws;
  _Float16* Qh    = (_Float16*)(ws);
  _Float16* Kh    = (_Float16*)(ws + (4u  << 20));
  _Float16* Vtg   = (_Float16*)(ws + (20u << 20));
  _Float16* Opart = (_Float16*)(ws + (36u << 20));
  float*    mlp   = (float*)   (ws + (52u << 20));
  _Float16* Wh    = (_Float16*)(ws + (53u << 20));

  _Float16* Whq = Wh;
  _Float16* Whk = Wh + 262144;
  _Float16* Whv = Wh + 524288;
  _Float16* Who = Wh + 786432;

  const float qscale = 0.08838834764831845f;  // 1/sqrt(128)
  dim3 blk(256);

  prep_w<<<dim3(1024), blk, 0, stream>>>(Wq, Wk, Wv, Wo, Wh);

  proj_qkv<<<dim3(160, 4), blk, 0, stream>>>(
      x, enc, Whq, Whk, Whv, bq, bk, bv, Qh, Kh, Vtg, qscale);

  flash_mfma2<<<dim3(64, 8), blk, 0, stream>>>(Qh, Kh, Vtg, Opart, mlp);

  proj_out_fused<<<dim3(64, 4), blk, 0, stream>>>(Opart, mlp, Who, bo, out);
}